// Round 6
// baseline (1817.435 us; speedup 1.0000x reference)
//
#include <hip/hip_runtime.h>

// AR LSTM decoder, B=256, T=2048, IN=64, H=32, NCLS=5.
// 3 waves per block (1 block per batch row):
//   wave1/wave2 (producers): gx[t][row] = W_ih[row,:64] @ x_t + bias, one
//     32-step chunk ahead into an LDS double buffer (R5-proven, unchanged).
//   wave0 (consumer): serial recurrence. KEY CHANGE vs R5: W_hh lives in LDS
//     (row stride 36 floats, staged once) and is re-read every step through a
//     laundered offset (asm volatile) so LICM cannot hoist it into registers.
//     R2/R4/R5 showed the allocator caps ~104-132 VGPRs and spills the rest
//     to scratch on the serial chain; consumer register demand is now ~100.

namespace {

typedef float f2 __attribute__((ext_vector_type(2)));
typedef unsigned int u32;
typedef const __attribute__((address_space(1))) u32* gas_ptr;
typedef __attribute__((address_space(3))) u32* las_ptr;

constexpr int Tn  = 2048;
constexpr int INn = 64;
constexpr int Hn  = 32;
constexpr int NC  = 5;
constexpr int CH  = 32;            // steps per chunk
constexpr int CHF = CH * INn;      // 2048 floats x-chunk (8 KB)
constexpr int GXF = CH * 128;      // 4096 floats gx-chunk (16 KB)
constexpr int NCHUNK = Tn / CH;    // 64
constexpr int WHS = 36;            // W_hh LDS row stride (pad 4: banks spread)

__device__ __forceinline__ float rcpf(float x) { return __builtin_amdgcn_rcpf(x); }
__device__ __forceinline__ float hadd(f2 v) { return v.x + v.y; }

template <int CTRL, int RM, int BM, bool BC>
__device__ __forceinline__ float dpp_add(float x) {
    int t = __builtin_amdgcn_update_dpp(0, __float_as_int(x), CTRL, RM, BM, BC);
    return x + __int_as_float(t);
}

// sum over all 64 lanes, broadcast via readlane(63)  [proven R2/R4/R5]
__device__ __forceinline__ float wave_sum64(float x) {
    x = dpp_add<0x111, 0xF, 0xF, true>(x);   // row_shr:1
    x = dpp_add<0x112, 0xF, 0xF, true>(x);   // row_shr:2
    x = dpp_add<0x114, 0xF, 0xF, true>(x);   // row_shr:4
    x = dpp_add<0x118, 0xF, 0xF, true>(x);   // row_shr:8
    x = dpp_add<0x142, 0xA, 0xF, false>(x);  // row_bcast15
    x = dpp_add<0x143, 0xC, 0xF, false>(x);  // row_bcast31 -> lane 63 total
    return __int_as_float(__builtin_amdgcn_readlane(__float_as_int(x), 63));
}

__device__ __forceinline__ float dpp_swap1(float x) {   // quad_perm xor 1
    int t = __builtin_amdgcn_update_dpp(0, __float_as_int(x), 0xB1, 0xF, 0xF, true);
    return __int_as_float(t);
}

__device__ __forceinline__ void gl16(const float* g, float* l) {
    __builtin_amdgcn_global_load_lds((gas_ptr)g, (las_ptr)l, 16, 0, 0);
}

__device__ __forceinline__ int ld_acq(int* p) {
    return __hip_atomic_load(p, __ATOMIC_ACQUIRE, __HIP_MEMORY_SCOPE_WORKGROUP);
}
__device__ __forceinline__ void st_rel(int* p, int v) {
    __hip_atomic_store(p, v, __ATOMIC_RELEASE, __HIP_MEMORY_SCOPE_WORKGROUP);
}

__global__ __launch_bounds__(192)
void ar_decode(const float* __restrict__ x,
               const float* __restrict__ W_ih,
               const float* __restrict__ W_hh,
               const float* __restrict__ b_ih,
               const float* __restrict__ b_hh,
               const float* __restrict__ W_fc,
               const float* __restrict__ b_fc,
               const float* __restrict__ emb,
               float* __restrict__ out)
{
    const int b    = blockIdx.x;
    const int tid  = threadIdx.x;
    const int wv   = tid >> 6;          // 0: consumer, 1/2: producers
    const int lane = tid & 63;
    const int m    = lane >> 1;
    const int par  = lane & 1;
    const bool even = (par == 0);
    const int rA = par * Hn + m;            // i-row (par0) or f-row (par1)
    const int rB = 2 * Hn + par * Hn + m;   // g-row (par0) or o-row (par1)

    __shared__ __align__(16) float s_xp[2 * 2 * CHF];  // 32 KB per-producer x dbuf
    __shared__ __align__(16) float s_gx[2 * GXF];      // 32 KB gx double buffer
    __shared__ __align__(16) float s_whh[128 * WHS];   // 18 KB W_hh (stride 36)
    __shared__ __align__(16) float s_h[Hn];
    __shared__ int s_p1, s_p2, s_cons;

    if (tid == 0) { s_p1 = 0; s_p2 = 0; s_cons = 0; }
    if (tid < Hn) s_h[tid] = 0.f;
    // stage W_hh -> LDS (rows 0..127, 32 floats each, stride 36)
    if (tid < 128) {
        const float4* src = (const float4*)(W_hh + (size_t)tid * Hn);
        float4* dst = (float4*)(s_whh + tid * WHS);   // 144 B stride, 16B-aligned
        #pragma unroll
        for (int i = 0; i < 8; ++i) dst[i] = src[i];
    }
    __syncthreads();

    const float* __restrict__ xb = x + (size_t)b * Tn * INn;

    if (wv != 0) {
        // ===================== producer wave (1 or 2), R5-proven =====================
        const int row = (wv - 1) * 64 + lane;     // one gate row per lane
        float* const s_xw = s_xp + (wv - 1) * (2 * CHF);  // private x dbuf
        int* const myflag = (wv == 1) ? &s_p1 : &s_p2;

        f2 wR[INn / 2];                            // 64 VGPR, volatile-pinned
        {
            const volatile f2* p = (const volatile f2*)(W_ih + (size_t)row * 2 * INn);
            #pragma unroll
            for (int i = 0; i < INn / 2; ++i) wR[i] = p[i];
        }
        const float bias = b_ih[row] + b_hh[row];

        #pragma unroll
        for (int r = 0; r < 8; ++r) gl16(xb + r * 256 + lane * 4, s_xw + r * 256);
        #pragma unroll
        for (int r = 0; r < 8; ++r) gl16(xb + CHF + r * 256 + lane * 4, s_xw + CHF + r * 256);

        for (int q = 0; q < NCHUNK; ++q) {
            if (q == NCHUNK - 1) asm volatile("s_waitcnt vmcnt(0)" ::: "memory");
            else                 asm volatile("s_waitcnt vmcnt(8)" ::: "memory");
            while (ld_acq(&s_cons) < q - 1) { }   // gx buf (q&1) free?

            const f2* xc  = (const f2*)(s_xw + (q & 1) * CHF);
            float*    gxd = s_gx + (q & 1) * GXF;
            #pragma unroll 2
            for (int s = 0; s < CH; ++s) {
                const f2* xt2 = xc + s * (INn / 2);
                f2 a0, a1, a2, a3;
                a0 = a1 = a2 = a3 = (f2)(0.f);
                #pragma unroll
                for (int i = 0; i < INn / 2; i += 4) {
                    a0 += wR[i]     * xt2[i];
                    a1 += wR[i + 1] * xt2[i + 1];
                    a2 += wR[i + 2] * xt2[i + 2];
                    a3 += wR[i + 3] * xt2[i + 3];
                }
                gxd[s * 128 + row] = bias + hadd((a0 + a1) + (a2 + a3));
            }
            if (lane == 0) st_rel(myflag, q + 1);
            if (q + 2 < NCHUNK) {
                const float* src = xb + (size_t)(q + 2) * CHF;
                float* dst = s_xw + (q & 1) * CHF;
                #pragma unroll
                for (int r = 0; r < 8; ++r) gl16(src + r * 256 + lane * 4, dst + r * 256);
            }
        }
    } else {
        // ===================== consumer wave (serial chain) =====================
        // P[cls] = ( dot(W_ih[rA,64:128], emb[cls]), dot(W_ih[rB,64:128], emb[cls]) )
        f2 P[NC];
        #pragma unroll
        for (int cls = 0; cls < NC; ++cls) {
            float pa = 0.f, pb = 0.f;
            for (int i = 0; i < INn; ++i) {
                const float e = emb[cls * INn + i];
                pa += W_ih[(size_t)rA * 2 * INn + INn + i] * e;
                pb += W_ih[(size_t)rB * 2 * INn + INn + i] * e;
            }
            f2 v; v.x = pa; v.y = pb; P[cls] = v;
        }

        const float wfc0 = 0.5f * W_fc[0 * Hn + m];
        const float wfc1 = 0.5f * W_fc[1 * Hn + m];
        const float wfc2 = 0.5f * W_fc[2 * Hn + m];
        const float wfc3 = 0.5f * W_fc[3 * Hn + m];
        const float wfc4 = 0.5f * W_fc[4 * Hn + m];
        const float bf0 = b_fc[0], bf1 = b_fc[1], bf2 = b_fc[2],
                    bf3 = b_fc[3], bf4 = b_fc[4];

        const float zsB  = even ? 2.f : 1.f;   // g: tanh(z) = 2*sig(2z)-1
        const float mulB = even ? 2.f : 1.f;
        const float addB = even ? -1.f : 0.f;

        float* __restrict__ ob = out + (size_t)b * Tn * NC;

        float c = 0.f;
        f2 Ps; Ps.x = 0.f; Ps.y = 0.f;

        for (int q = 0; q < NCHUNK; ++q) {
            while (ld_acq(&s_p1) < q + 1) { }        // wait for gx chunk q
            while (ld_acq(&s_p2) < q + 1) { }
            const float* gxc = s_gx + (q & 1) * GXF;

            #pragma unroll 2
            for (int s = 0; s < CH; ++s) {
                // launder the W_hh offset so LICM can't hoist the LDS reads
                // back into (spilled) registers
                int off = 0;
                asm volatile("" : "+v"(off));
                const f2* wa = (const f2*)(s_whh + rA * WHS) + off;
                const f2* wb = (const f2*)(s_whh + rB * WHS) + off;

                // gate inputs from producers (off the h-chain)
                const float gA = gxc[s * 128 + rA];
                const float gB = gxc[s * 128 + rB];

                // h broadcast from LDS (previous step's h)
                const f2* h2 = (const f2*)s_h;

                // W_hh · h (4 chains per row), weights streamed from LDS
                f2 aA0, aA1, aA2, aA3, aB0, aB1, aB2, aB3;
                aA0 = aA1 = aA2 = aA3 = aB0 = aB1 = aB2 = aB3 = (f2)(0.f);
                #pragma unroll
                for (int i = 0; i < Hn / 2; i += 4) {
                    const f2 h0 = h2[i], h1 = h2[i + 1], h3 = h2[i + 2], h4 = h2[i + 3];
                    aA0 += wa[i] * h0;     aB0 += wb[i] * h0;
                    aA1 += wa[i + 1] * h1; aB1 += wb[i + 1] * h1;
                    aA2 += wa[i + 2] * h3; aB2 += wb[i + 2] * h3;
                    aA3 += wa[i + 3] * h4; aB3 += wb[i + 3] * h4;
                }
                const float accA = (gA + Ps.x) + hadd((aA0 + aA1) + (aA2 + aA3));
                const float accB = (gB + Ps.y) + hadd((aB0 + aB1) + (aB2 + aB3));

                // activations: A = sigmoid (i/f); B = tanh (g) / sigmoid (o)
                const float actA = rcpf(1.f + __expf(-accA));
                const float sgB  = rcpf(1.f + __expf(-zsB * accB));
                const float actB = fmaf(sgB, mulB, addB);

                // pair exchange (xor 1)
                const float qA = dpp_swap1(actA);
                const float qB = dpp_swap1(actB);
                const float iv = even ? actA : qA;
                const float fv = even ? qA : actA;
                const float gv = even ? actB : qB;
                const float ov = even ? qB : actB;

                // cell update (redundant in both parities -> identical)
                c = fmaf(fv, c, iv * gv);
                const float e2 = __expf(2.f * c);
                const float th = 1.f - 2.f * rcpf(e2 + 1.f);
                const float h  = ov * th;
                if (even) s_h[m] = h;     // for next step's matvec

                // logits from the fresh in-register h
                float p0 = wave_sum64(h * wfc0) + bf0;
                float p1 = wave_sum64(h * wfc1) + bf1;
                float p2 = wave_sum64(h * wfc2) + bf2;
                float p3 = wave_sum64(h * wfc3) + bf3;
                float p4 = wave_sum64(h * wfc4) + bf4;

                // argmax (first-max-wins, matches np.argmax)
                int am = 0; float bv = p0;
                if (p1 > bv) { bv = p1; am = 1; }
                if (p2 > bv) { bv = p2; am = 2; }
                if (p3 > bv) { bv = p3; am = 3; }
                if (p4 > bv) { bv = p4; am = 4; }

                // next-step prev-embedding contribution
                Ps = (am == 0) ? P[0] : (am == 1) ? P[1] : (am == 2) ? P[2]
                   : (am == 3) ? P[3] : P[4];

                // log-softmax + store (off-chain)
                const float se = __expf(p0 - bv) + __expf(p1 - bv) + __expf(p2 - bv)
                               + __expf(p3 - bv) + __expf(p4 - bv);
                const float lse = bv + __logf(se);
                if (lane < NC) {
                    float pv = p0;
                    pv = (lane == 1) ? p1 : pv;
                    pv = (lane == 2) ? p2 : pv;
                    pv = (lane == 3) ? p3 : pv;
                    pv = (lane == 4) ? p4 : pv;
                    ob[(size_t)(q * CH + s) * NC + lane] = pv - lse;
                }
            }
            if (lane == 0) st_rel(&s_cons, q + 1);   // gx buf (q&1) free
        }
    }
}

} // namespace

extern "C" void kernel_launch(void* const* d_in, const int* in_sizes, int n_in,
                              void* d_out, int out_size, void* d_ws, size_t ws_size,
                              hipStream_t stream) {
    (void)in_sizes; (void)n_in; (void)d_ws; (void)ws_size; (void)out_size;
    const float* x    = (const float*)d_in[0];
    // d_in[1] x_lengths (all == T), d_in[2] edge_list: unused
    const float* W_ih = (const float*)d_in[3];
    const float* W_hh = (const float*)d_in[4];
    const float* b_ih = (const float*)d_in[5];
    const float* b_hh = (const float*)d_in[6];
    const float* W_fc = (const float*)d_in[7];
    const float* b_fc = (const float*)d_in[8];
    const float* emb  = (const float*)d_in[9];
    float* out = (float*)d_out;

    hipLaunchKernelGGL(ar_decode, dim3(256), dim3(192), 0, stream,
                       x, W_ih, W_hh, b_ih, b_hh, W_fc, b_fc, emb, out);
}

// Round 7
// 1456.014 us; speedup vs baseline: 1.2482x; 1.2482x over previous
//
#include <hip/hip_runtime.h>

// AR LSTM decoder, B=256, T=2048, IN=64, H=32, NCLS=5.
// 3 waves per block (1 block per batch row):
//   wave1/wave2 (producers): gx[t][row] = W_ih[row,:64] @ x_t + bias, one
//     32-step chunk ahead into an LDS double buffer (R5-proven, unchanged).
//   wave0 (consumer): serial recurrence, K-HALF SPLIT mapping to fit the
//     ~128-VGPR allocator comfort zone with W_hh register-resident:
//     lane pair (2m, 2m+1) both own gate rows {i_m, f_m, g_m, o_m}; par=0
//     accumulates k in [0,16), par=1 k in [16,32). gx + P[argmax] constants
//     folded once per pair (even: i,f rows; odd: g,o rows). Pair merge via 4
//     quad_perm-xor1 DPP adds. Activation/exchange/c/h/logits path identical
//     to R4 (proven numerics). W_hh stays in VGPRs: R6 showed streaming it
//     from LDS costs >=128 cyc/step of LDS BW plus 8-way conflicts.

namespace {

typedef float f2 __attribute__((ext_vector_type(2)));
typedef unsigned int u32;
typedef const __attribute__((address_space(1))) u32* gas_ptr;
typedef __attribute__((address_space(3))) u32* las_ptr;

constexpr int Tn  = 2048;
constexpr int INn = 64;
constexpr int Hn  = 32;
constexpr int NC  = 5;
constexpr int CH  = 32;            // steps per chunk
constexpr int CHF = CH * INn;      // 2048 floats x-chunk (8 KB)
constexpr int GXF = CH * 128;      // 4096 floats gx-chunk (16 KB)
constexpr int NCHUNK = Tn / CH;    // 64

__device__ __forceinline__ float rcpf(float x) { return __builtin_amdgcn_rcpf(x); }
__device__ __forceinline__ float hadd(f2 v) { return v.x + v.y; }

template <int CTRL, int RM, int BM, bool BC>
__device__ __forceinline__ float dpp_add_t(float x) {
    int t = __builtin_amdgcn_update_dpp(0, __float_as_int(x), CTRL, RM, BM, BC);
    return x + __int_as_float(t);
}

// sum over all 64 lanes, broadcast via readlane(63)  [proven R2/R4/R5]
__device__ __forceinline__ float wave_sum64(float x) {
    x = dpp_add_t<0x111, 0xF, 0xF, true>(x);   // row_shr:1
    x = dpp_add_t<0x112, 0xF, 0xF, true>(x);   // row_shr:2
    x = dpp_add_t<0x114, 0xF, 0xF, true>(x);   // row_shr:4
    x = dpp_add_t<0x118, 0xF, 0xF, true>(x);   // row_shr:8
    x = dpp_add_t<0x142, 0xA, 0xF, false>(x);  // row_bcast15
    x = dpp_add_t<0x143, 0xC, 0xF, false>(x);  // row_bcast31 -> lane 63 total
    return __int_as_float(__builtin_amdgcn_readlane(__float_as_int(x), 63));
}

__device__ __forceinline__ float dpp_swap1(float x) {   // quad_perm xor 1
    int t = __builtin_amdgcn_update_dpp(0, __float_as_int(x), 0xB1, 0xF, 0xF, true);
    return __int_as_float(t);
}
__device__ __forceinline__ float pair_sum(float x) {    // x + partner(x)
    return x + dpp_swap1(x);
}

__device__ __forceinline__ void gl16(const float* g, float* l) {
    __builtin_amdgcn_global_load_lds((gas_ptr)g, (las_ptr)l, 16, 0, 0);
}

__device__ __forceinline__ int ld_acq(int* p) {
    return __hip_atomic_load(p, __ATOMIC_ACQUIRE, __HIP_MEMORY_SCOPE_WORKGROUP);
}
__device__ __forceinline__ void st_rel(int* p, int v) {
    __hip_atomic_store(p, v, __ATOMIC_RELEASE, __HIP_MEMORY_SCOPE_WORKGROUP);
}

__global__ __launch_bounds__(192)
void ar_decode(const float* __restrict__ x,
               const float* __restrict__ W_ih,
               const float* __restrict__ W_hh,
               const float* __restrict__ b_ih,
               const float* __restrict__ b_hh,
               const float* __restrict__ W_fc,
               const float* __restrict__ b_fc,
               const float* __restrict__ emb,
               float* __restrict__ out)
{
    const int b    = blockIdx.x;
    const int tid  = threadIdx.x;
    const int wv   = tid >> 6;          // 0: consumer, 1/2: producers
    const int lane = tid & 63;
    const int m    = lane >> 1;
    const int par  = lane & 1;
    const bool even = (par == 0);

    __shared__ __align__(16) float s_xp[2 * 2 * CHF];  // 32 KB per-producer x dbuf
    __shared__ __align__(16) float s_gx[2 * GXF];      // 32 KB gx double buffer
    __shared__ __align__(16) float s_h[Hn];
    __shared__ int s_p1, s_p2, s_cons;

    if (tid == 0) { s_p1 = 0; s_p2 = 0; s_cons = 0; }
    if (tid < Hn) s_h[tid] = 0.f;
    __syncthreads();

    const float* __restrict__ xb = x + (size_t)b * Tn * INn;

    if (wv != 0) {
        // ===================== producer wave (1 or 2), R5-proven =====================
        const int row = (wv - 1) * 64 + lane;     // one gate row per lane
        float* const s_xw = s_xp + (wv - 1) * (2 * CHF);  // private x dbuf
        int* const myflag = (wv == 1) ? &s_p1 : &s_p2;

        f2 wR[INn / 2];                            // 64 VGPR, volatile-pinned
        {
            const volatile f2* p = (const volatile f2*)(W_ih + (size_t)row * 2 * INn);
            #pragma unroll
            for (int i = 0; i < INn / 2; ++i) wR[i] = p[i];
        }
        const float bias = b_ih[row] + b_hh[row];

        #pragma unroll
        for (int r = 0; r < 8; ++r) gl16(xb + r * 256 + lane * 4, s_xw + r * 256);
        #pragma unroll
        for (int r = 0; r < 8; ++r) gl16(xb + CHF + r * 256 + lane * 4, s_xw + CHF + r * 256);

        for (int q = 0; q < NCHUNK; ++q) {
            if (q == NCHUNK - 1) asm volatile("s_waitcnt vmcnt(0)" ::: "memory");
            else                 asm volatile("s_waitcnt vmcnt(8)" ::: "memory");
            while (ld_acq(&s_cons) < q - 1) { }   // gx buf (q&1) free?

            const f2* xc  = (const f2*)(s_xw + (q & 1) * CHF);
            float*    gxd = s_gx + (q & 1) * GXF;
            #pragma unroll 2
            for (int s = 0; s < CH; ++s) {
                const f2* xt2 = xc + s * (INn / 2);
                f2 a0, a1, a2, a3;
                a0 = a1 = a2 = a3 = (f2)(0.f);
                #pragma unroll
                for (int i = 0; i < INn / 2; i += 4) {
                    a0 += wR[i]     * xt2[i];
                    a1 += wR[i + 1] * xt2[i + 1];
                    a2 += wR[i + 2] * xt2[i + 2];
                    a3 += wR[i + 3] * xt2[i + 3];
                }
                gxd[s * 128 + row] = bias + hadd((a0 + a1) + (a2 + a3));
            }
            if (lane == 0) st_rel(myflag, q + 1);
            if (q + 2 < NCHUNK) {
                const float* src = xb + (size_t)(q + 2) * CHF;
                float* dst = s_xw + (q & 1) * CHF;
                #pragma unroll
                for (int r = 0; r < 8; ++r) gl16(src + r * 256 + lane * 4, dst + r * 256);
            }
        }
    } else {
        // ===================== consumer wave (serial chain) =====================
        // Rows of hidden unit m: i=m, f=32+m, g=64+m, o=96+m.
        // This lane's k-half: k in [par*16, par*16+16)  -> f2 index par*8.
        const int kb = par * (Hn / 2);             // float offset into h

        // W_hh k-half weights, 4 rows x 8 f2 = 64 VGPR, volatile-pinned
        f2 wI[8], wF[8], wG[8], wO[8];
        {
            const volatile f2* pI = (const volatile f2*)(W_hh + (size_t)(0 * Hn + m) * Hn + kb);
            const volatile f2* pF = (const volatile f2*)(W_hh + (size_t)(1 * Hn + m) * Hn + kb);
            const volatile f2* pG = (const volatile f2*)(W_hh + (size_t)(2 * Hn + m) * Hn + kb);
            const volatile f2* pO = (const volatile f2*)(W_hh + (size_t)(3 * Hn + m) * Hn + kb);
            #pragma unroll
            for (int i = 0; i < 8; ++i) { wI[i] = pI[i]; wF[i] = pF[i]; wG[i] = pG[i]; wO[i] = pO[i]; }
        }

        // gx/P fold rows for this lane: even -> (i,f); odd -> (g,o)
        const int rF0 = even ? m : 2 * Hn + m;          // i_m  or g_m
        const int rF1 = even ? Hn + m : 3 * Hn + m;     // f_m  or o_m

        // P[cls] = ( dot(W_ih[rF0,64:128], emb[cls]), dot(W_ih[rF1,64:128], emb[cls]) )
        f2 P[NC];
        #pragma unroll
        for (int cls = 0; cls < NC; ++cls) {
            float pa = 0.f, pb = 0.f;
            for (int i = 0; i < INn; ++i) {
                const float e = emb[cls * INn + i];
                pa += W_ih[(size_t)rF0 * 2 * INn + INn + i] * e;
                pb += W_ih[(size_t)rF1 * 2 * INn + INn + i] * e;
            }
            f2 v; v.x = pa; v.y = pb; P[cls] = v;
        }

        // classifier: lane holds 0.5*W_fc[cls][m] (h duplicated on parities)
        const float wfc0 = 0.5f * W_fc[0 * Hn + m];
        const float wfc1 = 0.5f * W_fc[1 * Hn + m];
        const float wfc2 = 0.5f * W_fc[2 * Hn + m];
        const float wfc3 = 0.5f * W_fc[3 * Hn + m];
        const float wfc4 = 0.5f * W_fc[4 * Hn + m];
        const float bf0 = b_fc[0], bf1 = b_fc[1], bf2 = b_fc[2],
                    bf3 = b_fc[3], bf4 = b_fc[4];

        // activation roles (identical to R4): even activates (i, g[tanh]);
        // odd activates (f, o). Exchange distributes.
        const float zsB  = even ? 2.f : 1.f;
        const float mulB = even ? 2.f : 1.f;
        const float addB = even ? -1.f : 0.f;

        float* __restrict__ ob = out + (size_t)b * Tn * NC;

        float c = 0.f;
        f2 Ps; Ps.x = 0.f; Ps.y = 0.f;

        for (int q = 0; q < NCHUNK; ++q) {
            while (ld_acq(&s_p1) < q + 1) { }        // wait for gx chunk q
            while (ld_acq(&s_p2) < q + 1) { }
            const float* gxc = s_gx + (q & 1) * GXF;

            #pragma unroll 2
            for (int s = 0; s < CH; ++s) {
                // gx constants for this lane's fold rows (off the h-chain)
                const float gx0 = gxc[s * 128 + rF0];
                const float gx1 = gxc[s * 128 + rF1];

                // h half from LDS (previous step's h), 4 b128 reads
                const f2* h2 = (const f2*)(s_h + kb);

                // W_hh · h, k-half, one chain per row (4-way ILP)
                f2 aI, aF, aG, aO;
                aI = aF = aG = aO = (f2)(0.f);
                #pragma unroll
                for (int i = 0; i < 8; ++i) {
                    const f2 hh = h2[i];
                    aI += wI[i] * hh;
                    aF += wF[i] * hh;
                    aG += wG[i] * hh;
                    aO += wO[i] * hh;
                }
                // this lane's half-sums; fold gx+P once per pair
                float hI = hadd(aI), hF = hadd(aF), hG = hadd(aG), hO = hadd(aO);
                if (even) { hI += gx0 + Ps.x; hF += gx1 + Ps.y; }
                else      { hG += gx0 + Ps.x; hO += gx1 + Ps.y; }

                // pair merge: full pre-activations on both lanes
                const float preI = pair_sum(hI);
                const float preF = pair_sum(hF);
                const float preG = pair_sum(hG);
                const float preO = pair_sum(hO);

                // activations split exactly as R4: even does (i, g), odd (f, o)
                const float preA = even ? preI : preF;
                const float preB = even ? preG : preO;
                const float actA = rcpf(1.f + __expf(-preA));
                const float sgB  = rcpf(1.f + __expf(-zsB * preB));
                const float actB = fmaf(sgB, mulB, addB);

                // exchange (xor 1)
                const float qA = dpp_swap1(actA);
                const float qB = dpp_swap1(actB);
                const float iv = even ? actA : qA;
                const float fv = even ? qA : actA;
                const float gv = even ? actB : qB;
                const float ov = even ? qB : actB;

                // cell update (redundant in both parities -> identical)
                c = fmaf(fv, c, iv * gv);
                const float e2 = __expf(2.f * c);
                const float th = 1.f - 2.f * rcpf(e2 + 1.f);
                const float h  = ov * th;
                if (even) s_h[m] = h;     // for next step's matvec

                // logits from the fresh in-register h  [R4-proven]
                float p0 = wave_sum64(h * wfc0) + bf0;
                float p1 = wave_sum64(h * wfc1) + bf1;
                float p2 = wave_sum64(h * wfc2) + bf2;
                float p3 = wave_sum64(h * wfc3) + bf3;
                float p4 = wave_sum64(h * wfc4) + bf4;

                // argmax (first-max-wins, matches np.argmax)
                int am = 0; float bv = p0;
                if (p1 > bv) { bv = p1; am = 1; }
                if (p2 > bv) { bv = p2; am = 2; }
                if (p3 > bv) { bv = p3; am = 3; }
                if (p4 > bv) { bv = p4; am = 4; }

                // next-step prev-embedding contribution
                Ps = (am == 0) ? P[0] : (am == 1) ? P[1] : (am == 2) ? P[2]
                   : (am == 3) ? P[3] : P[4];

                // log-softmax + store (off-chain)
                const float se = __expf(p0 - bv) + __expf(p1 - bv) + __expf(p2 - bv)
                               + __expf(p3 - bv) + __expf(p4 - bv);
                const float lse = bv + __logf(se);
                if (lane < NC) {
                    float pv = p0;
                    pv = (lane == 1) ? p1 : pv;
                    pv = (lane == 2) ? p2 : pv;
                    pv = (lane == 3) ? p3 : pv;
                    pv = (lane == 4) ? p4 : pv;
                    ob[(size_t)(q * CH + s) * NC + lane] = pv - lse;
                }
            }
            if (lane == 0) st_rel(&s_cons, q + 1);   // gx buf (q&1) free
        }
    }
}

} // namespace

extern "C" void kernel_launch(void* const* d_in, const int* in_sizes, int n_in,
                              void* d_out, int out_size, void* d_ws, size_t ws_size,
                              hipStream_t stream) {
    (void)in_sizes; (void)n_in; (void)d_ws; (void)ws_size; (void)out_size;
    const float* x    = (const float*)d_in[0];
    // d_in[1] x_lengths (all == T), d_in[2] edge_list: unused
    const float* W_ih = (const float*)d_in[3];
    const float* W_hh = (const float*)d_in[4];
    const float* b_ih = (const float*)d_in[5];
    const float* b_hh = (const float*)d_in[6];
    const float* W_fc = (const float*)d_in[7];
    const float* b_fc = (const float*)d_in[8];
    const float* emb  = (const float*)d_in[9];
    float* out = (float*)d_out;

    hipLaunchKernelGGL(ar_decode, dim3(256), dim3(192), 0, stream,
                       x, W_ih, W_hh, b_ih, b_hh, W_fc, b_fc, emb, out);
}